// Round 1
// baseline (333.328 us; speedup 1.0000x reference)
//
#include <hip/hip_runtime.h>

#define SPS    16
#define NS     8192            // symbols per batch row
#define NBITS  16384           // bits per batch row
#define UPLEN  (NS * SPS)      // 131072
#define KTAPS  128
#define QPB    256             // symbols (q values) handled per block
#define SWIN   264             // QPB + 8 halo

typedef float vfloat4 __attribute__((ext_vector_type(4)));
typedef float vfloat2 __attribute__((ext_vector_type(2)));

// R7: 4 phases per thread. Thread (gg = tid>>2, k = tid&3) computes phases
// p = 4k..4k+3 (both channels) of q = q0 + G*64 + gg, G = 0..3.
//
// Sample t=16q+p needs taps rrc[16i+7-p] (p<8, symbol q+i-4) or
// rrc[16i+23-p] (p>=8, symbol q+i-3), i=0..7. For the 4-phase group:
//   base = k<2 ? 4-4k : 20-4k   -> float4 tap quad s_taps[16i+base..base+3],
//   tap for sub-phase c (=0..3) is element [3-c];  sel = (k>=2) folded into
//   the LDS window base. Taps: 8 x ds_read_b128 (16B-aligned: base in
//   {0,4,8,12} floats). Symbols interleaved (re,im) -> 1 x ds_read_b64 each.
// Per-thread LDS mainloop: 32 b64 + 8 b128 (vs 128 b32 + 8 b64 in R6).
//
// Store: 8 floats/thread/q at out float offset 32q + 8k, as two float4 NT
// stores; a wave's store pair tiles a contiguous 2 KB span.
__global__ __launch_bounds__(256, 4)
void qpsk_mod_kernel(const int* __restrict__ bits,
                     const float* __restrict__ rrc,
                     float* __restrict__ out) {
    __shared__ __align__(16) float s_taps[KTAPS];
    __shared__ vfloat2 s_sym[SWIN];

    const int tid = threadIdx.x;
    const int b   = blockIdx.x >> 5;           // 32 blocks per batch row
    const int q0  = (blockIdx.x & 31) * QPB;

    if (tid < KTAPS) s_taps[tid] = rrc[tid];

    const float scale = 2.82842712474619f;     // 4 / sqrt(2): sqrt(sps)/sqrt(2)
    for (int ls = tid; ls < SWIN; ls += 256) {
        int s = q0 - 4 + ls;                   // global symbol index
        vfloat2 v = {0.f, 0.f};
        if (s >= 0 && s < NS) {
            int2 bb = *(const int2*)(bits + b * NBITS + 2 * s);
            v.x = (float)(1 - 2 * bb.y) * scale;   // re
            v.y = (float)(1 - 2 * bb.x) * scale;   // im
        }
        s_sym[ls] = v;
    }
    __syncthreads();

    const int k    = tid & 3;
    const int gg   = tid >> 2;                 // 0..63
    const int base = (k < 2) ? (4 - 4 * k) : (20 - 4 * k);   // 4,0,12,8
    const int sel  = (k >= 2) ? 1 : 0;

    // tap quads: element [3-c] is the tap for sub-phase c
    vfloat4 t4[8];
#pragma unroll
    for (int i = 0; i < 8; ++i)
        t4[i] = *(const vfloat4*)(&s_taps[16 * i + base]);

    float* outp = out + (size_t)b * (UPLEN * 2)
                      + (size_t)(q0 + gg) * 32 + 8 * k;

#pragma unroll
    for (int G = 0; G < 4; ++G) {
        const int wbase = G * 64 + gg + sel;   // LDS index of symbol q-4+sel
        float a0 = 0.f, a1 = 0.f, a2 = 0.f, a3 = 0.f;
        float a4 = 0.f, a5 = 0.f, a6 = 0.f, a7 = 0.f;
#pragma unroll
        for (int i = 0; i < 8; ++i) {
            vfloat2 s = s_sym[wbase + i];
            vfloat4 t = t4[i];
            a0 += t.w * s.x;  a1 += t.w * s.y;   // c=0: re, im
            a2 += t.z * s.x;  a3 += t.z * s.y;   // c=1
            a4 += t.y * s.x;  a5 += t.y * s.y;   // c=2
            a6 += t.x * s.x;  a7 += t.x * s.y;   // c=3
        }
        vfloat4 v0 = {a0, a1, a2, a3};
        vfloat4 v1 = {a4, a5, a6, a7};
        float* p = outp + (size_t)G * 2048;    // q advances 64 -> 64*32 floats
        __builtin_nontemporal_store(v0, (vfloat4*)p);
        __builtin_nontemporal_store(v1, (vfloat4*)(p + 4));
    }
}

extern "C" void kernel_launch(void* const* d_in, const int* in_sizes, int n_in,
                              void* d_out, int out_size, void* d_ws, size_t ws_size,
                              hipStream_t stream) {
    const int*   bits = (const int*)d_in[0];
    const float* rrc  = (const float*)d_in[1];
    float*       out  = (float*)d_out;

    const int B = in_sizes[0] / NBITS;         // 256
    dim3 grid(B * (NS / QPB));                 // 8192 blocks
    qpsk_mod_kernel<<<grid, 256, 0, stream>>>(bits, rrc, out);
}

// Round 2
// 276.750 us; speedup vs baseline: 1.2044x; 1.2044x over previous
//
#include <hip/hip_runtime.h>

#define SPS    16
#define NS     8192            // symbols per batch row
#define NBITS  16384           // bits per batch row
#define UPLEN  (NS * SPS)      // 131072
#define KTAPS  128
#define QPB    256             // symbols (q values) handled per block
#define SWIN   264             // QPB + 8 halo

typedef float vfloat4 __attribute__((ext_vector_type(4)));
typedef float vfloat2 __attribute__((ext_vector_type(2)));

// R8: R6's verified phase-pair structure + contiguous 1-KB NT store bursts
// (lane-stride exactly 16 B), with R7's interleaved float2 symbol LDS so the
// main loop issues one ds_read_b64 per symbol instead of two ds_read_b32.
// Per-thread LDS main loop: 64 b64 (symbols) + 8 b64 (taps) = 72 instructions
// vs R6's 136.
//
// Thread (gg = tid>>3, k = tid&7) computes phases (2k, 2k+1) of
// q = q0 + G*32 + gg, G = 0..7.
// Sample t=16q+p needs taps rrc[16i + 7-p] (p<8, symbol q+i-4) or
// rrc[16i + 23-p] (p>=8, symbol q+i-3), i=0..7. For the fixed phase pair:
//   off = k<4 ? 6-2k : 22-2k;  tap rrc[16i+off+1] -> phase 2k,
//                              tap rrc[16i+off]   -> phase 2k+1
//   sel = (k>=4) folded into the LDS window base address.
// Per-wave symbol reads hit 9 distinct consecutive float2 addresses ->
// 18 distinct banks, conflict-free broadcast.
__global__ __launch_bounds__(256, 4)
void qpsk_mod_kernel(const int* __restrict__ bits,
                     const float* __restrict__ rrc,
                     float* __restrict__ out) {
    __shared__ __align__(16) float s_taps[KTAPS];
    __shared__ __align__(16) vfloat2 s_sym[SWIN];

    const int tid = threadIdx.x;
    const int b   = blockIdx.x >> 5;           // 32 blocks per batch row
    const int q0  = (blockIdx.x & 31) * QPB;

    if (tid < KTAPS) s_taps[tid] = rrc[tid];

    const float scale = 2.82842712474619f;     // 4 / sqrt(2): sqrt(sps)/sqrt(2)
    for (int ls = tid; ls < SWIN; ls += 256) {
        int s = q0 - 4 + ls;                   // global symbol index
        vfloat2 v = {0.f, 0.f};
        if (s >= 0 && s < NS) {
            int2 bb = *(const int2*)(bits + b * NBITS + 2 * s);
            v.x = (float)(1 - 2 * bb.y) * scale;   // re
            v.y = (float)(1 - 2 * bb.x) * scale;   // im
        }
        s_sym[ls] = v;
    }
    __syncthreads();

    const int k   = tid & 7;
    const int gg  = tid >> 3;                  // 0..31
    const int off = (k < 4) ? (6 - 2 * k) : (22 - 2 * k);
    const int sel = (k >= 4) ? 1 : 0;

    // taps: one pair per tap-group (8 x ds_read_b64, 8-lane broadcast)
    float tlo[8], thi[8];
#pragma unroll
    for (int i = 0; i < 8; ++i) {
        float2 tp = *(const float2*)(&s_taps[16 * i + off]);
        tlo[i] = tp.x;                         // -> phase 2k+1
        thi[i] = tp.y;                         // -> phase 2k
    }

    float* outp = out + (size_t)b * (UPLEN * 2)
                      + (size_t)(q0 + gg) * 32 + 4 * k;

#pragma unroll
    for (int G = 0; G < 8; ++G) {
        const int wbase = G * 32 + gg + sel;   // LDS index of symbol q-4+sel
        float a0 = 0.f, a1 = 0.f, a2 = 0.f, a3 = 0.f;
#pragma unroll
        for (int i = 0; i < 8; ++i) {
            vfloat2 s = s_sym[wbase + i];
            a0 += thi[i] * s.x;                // re, phase 2k
            a1 += thi[i] * s.y;                // im, phase 2k
            a2 += tlo[i] * s.x;                // re, phase 2k+1
            a3 += tlo[i] * s.y;                // im, phase 2k+1
        }
        vfloat4 v = {a0, a1, a2, a3};
        __builtin_nontemporal_store(v, (vfloat4*)(outp + G * (32 * 32)));
    }
}

extern "C" void kernel_launch(void* const* d_in, const int* in_sizes, int n_in,
                              void* d_out, int out_size, void* d_ws, size_t ws_size,
                              hipStream_t stream) {
    const int*   bits = (const int*)d_in[0];
    const float* rrc  = (const float*)d_in[1];
    float*       out  = (float*)d_out;

    const int B = in_sizes[0] / NBITS;         // 256
    dim3 grid(B * (NS / QPB));                 // 8192 blocks
    qpsk_mod_kernel<<<grid, 256, 0, stream>>>(bits, rrc, out);
}

// Round 3
// 273.612 us; speedup vs baseline: 1.2183x; 1.0115x over previous
//
#include <hip/hip_runtime.h>

#define SPS    16
#define NS     8192            // symbols per batch row
#define NBITS  16384           // bits per batch row
#define UPLEN  (NS * SPS)      // 131072
#define KTAPS  128
#define QPB    256             // symbols (q values) handled per block
#define SWIN   264             // QPB + 8 halo

typedef float vfloat4 __attribute__((ext_vector_type(4)));
typedef float vfloat2 __attribute__((ext_vector_type(2)));

// R9: identical to R8 except the NT store hint is removed (plain vector
// stores through L2, the same path the 6.3-TB/s fill uses). Single-variable
// experiment: discriminates "kernel already at write roofline" (no change)
// from "NT store path underperforms" (~-50 us).
//
// Thread (gg = tid>>3, k = tid&7) computes phases (2k, 2k+1) of
// q = q0 + G*32 + gg, G = 0..7.
// Sample t=16q+p needs taps rrc[16i + 7-p] (p<8, symbol q+i-4) or
// rrc[16i + 23-p] (p>=8, symbol q+i-3), i=0..7. For the fixed phase pair:
//   off = k<4 ? 6-2k : 22-2k;  tap rrc[16i+off+1] -> phase 2k,
//                              tap rrc[16i+off]   -> phase 2k+1
//   sel = (k>=4) folded into the LDS window base address.
__global__ __launch_bounds__(256, 4)
void qpsk_mod_kernel(const int* __restrict__ bits,
                     const float* __restrict__ rrc,
                     float* __restrict__ out) {
    __shared__ __align__(16) float s_taps[KTAPS];
    __shared__ __align__(16) vfloat2 s_sym[SWIN];

    const int tid = threadIdx.x;
    const int b   = blockIdx.x >> 5;           // 32 blocks per batch row
    const int q0  = (blockIdx.x & 31) * QPB;

    if (tid < KTAPS) s_taps[tid] = rrc[tid];

    const float scale = 2.82842712474619f;     // 4 / sqrt(2): sqrt(sps)/sqrt(2)
    for (int ls = tid; ls < SWIN; ls += 256) {
        int s = q0 - 4 + ls;                   // global symbol index
        vfloat2 v = {0.f, 0.f};
        if (s >= 0 && s < NS) {
            int2 bb = *(const int2*)(bits + b * NBITS + 2 * s);
            v.x = (float)(1 - 2 * bb.y) * scale;   // re
            v.y = (float)(1 - 2 * bb.x) * scale;   // im
        }
        s_sym[ls] = v;
    }
    __syncthreads();

    const int k   = tid & 7;
    const int gg  = tid >> 3;                  // 0..31
    const int off = (k < 4) ? (6 - 2 * k) : (22 - 2 * k);
    const int sel = (k >= 4) ? 1 : 0;

    // taps: one pair per tap-group (8 x ds_read_b64, 8-lane broadcast)
    float tlo[8], thi[8];
#pragma unroll
    for (int i = 0; i < 8; ++i) {
        float2 tp = *(const float2*)(&s_taps[16 * i + off]);
        tlo[i] = tp.x;                         // -> phase 2k+1
        thi[i] = tp.y;                         // -> phase 2k
    }

    float* outp = out + (size_t)b * (UPLEN * 2)
                      + (size_t)(q0 + gg) * 32 + 4 * k;

#pragma unroll
    for (int G = 0; G < 8; ++G) {
        const int wbase = G * 32 + gg + sel;   // LDS index of symbol q-4+sel
        float a0 = 0.f, a1 = 0.f, a2 = 0.f, a3 = 0.f;
#pragma unroll
        for (int i = 0; i < 8; ++i) {
            vfloat2 s = s_sym[wbase + i];
            a0 += thi[i] * s.x;                // re, phase 2k
            a1 += thi[i] * s.y;                // im, phase 2k
            a2 += tlo[i] * s.x;                // re, phase 2k+1
            a3 += tlo[i] * s.y;                // im, phase 2k+1
        }
        vfloat4 v = {a0, a1, a2, a3};
        *(vfloat4*)(outp + G * (32 * 32)) = v; // plain store (via L2)
    }
}

extern "C" void kernel_launch(void* const* d_in, const int* in_sizes, int n_in,
                              void* d_out, int out_size, void* d_ws, size_t ws_size,
                              hipStream_t stream) {
    const int*   bits = (const int*)d_in[0];
    const float* rrc  = (const float*)d_in[1];
    float*       out  = (float*)d_out;

    const int B = in_sizes[0] / NBITS;         // 256
    dim3 grid(B * (NS / QPB));                 // 8192 blocks
    qpsk_mod_kernel<<<grid, 256, 0, stream>>>(bits, rrc, out);
}